// Round 9
// baseline (15501.520 us; speedup 1.0000x reference)
//
#include <hip/hip_runtime.h>
#include <hip/hip_bf16.h>

#define B_   64
#define S_   1024
#define D_   512
#define H_   512
#define NWG  64     // WG = (rc, cs-group of 4); 4 waves = 4 cs slices
#define NCS  64     // column slices
#define HCW  8      // h-columns per col-slice
#define NT   256

typedef __attribute__((ext_vector_type(8))) short short8;
typedef __attribute__((ext_vector_type(4))) float f32x4;

__device__ __forceinline__ float sigm(float v) { return 1.0f / (1.0f + __expf(-v)); }
__device__ __forceinline__ float tanh_(float v) { return 1.0f - 2.0f / (__expf(2.0f * v) + 1.0f); }
__device__ __forceinline__ short f2bf(float f) {
  __hip_bfloat16 h = __float2bfloat16(f);
  short s;
  __builtin_memcpy(&s, &h, 2);
  return s;
}

union U128 { unsigned long long u[2]; unsigned int w[4]; short8 s; };

// DEVICE-scope (sc1) 16B store: bypasses the XCD-private L2, resolves at the
// on-die LLC. Single transaction -> tag+data atomic.
__device__ __forceinline__ void store_b128_dev(void* p, short8 v) {
  asm volatile("global_store_dwordx4 %0, %1, off sc1" :: "v"(p), "v"(v) : "memory");
}

// ---------------------------------------------------------------------------
// Prep: Wt[(cs*32+gc)][k] bf16, k=0..1023 — the transposed W fragment store
// (same content the old per-WG LDS tile held, now global + L2-cached).
// gc: 0-7 -> Wf cols, 8-15 -> Wi, 16-23 -> Wc, 24-31 -> Wo; col = cs*8+(gc&7).
// ---------------------------------------------------------------------------
__global__ __launch_bounds__(256, 1) void lstm_wprep(
    const float* __restrict__ Wf, const float* __restrict__ Wi,
    const float* __restrict__ Wc, const float* __restrict__ Wo,
    short* __restrict__ Wt)
{
  const int r   = blockIdx.x * 256 + threadIdx.x;   // 0..2047 = (cs,gc)
  const int gc  = r & 31;
  const int cs  = r >> 5;
  const float* Wg4[4] = {Wf, Wi, Wc, Wo};
  const float* src = Wg4[gc >> 3] + (cs * HCW + (gc & 7));
  short* dst = Wt + (size_t)r * 1024;
  for (int k0 = 0; k0 < 1024; k0 += 8) {
    short8 v;
#pragma unroll
    for (int j = 0; j < 8; ++j) v[j] = f2bf(src[(size_t)(k0 + j) * H_]);
    *(short8*)(dst + k0) = v;
  }
}

// ---------------------------------------------------------------------------
// Persistent recurrence, cooperative-WG form.
// WG = (rc, csg): 4 waves, wave w computes cs = csg*4+w. The 4 waves need the
// SAME h records (rows of cohort rc, all 64 cs) -> ONE cooperative tagged
// poll per WG: thread ti loads a contiguous 128B (8 records), tag-checks,
// cross-wave AND via LDS, then stages the 8B data words into the LDS h tile.
// Chip-wide poll traffic: 64 WG x 256 contiguous lines = ~16K line-reqs per
// attempt (vs ~500K scattered before) — attacking the LLC request-rate bound.
// ---------------------------------------------------------------------------
__global__ __launch_bounds__(NT, 1) void lstm_persist(
    const float* __restrict__ xg,
    const float* __restrict__ bfv, const float* __restrict__ biv,
    const float* __restrict__ bcv, const float* __restrict__ bov,
    const short* __restrict__ Wt,
    float* __restrict__ out,
    char* __restrict__ hbc)   // [2][64 rows][64 cs][2 quads][16B] tagged records
{
  __shared__ short hstage[16 * 520];   // 16 rows x 1040B (520 shorts) = 16.25KB
  __shared__ int   lflag[4];

  const int ti   = threadIdx.x;
  const int wg   = blockIdx.x;
  const int csg  = wg >> 2;          // cs group 0..15
  const int rc   = wg & 3;           // row cohort 0..3 (16 batch rows)
  const int wid  = ti >> 6;
  const int lane = ti & 63;
  const int cs   = (csg << 2) + wid; // this wave's column slice

  // Transposed-C lane mapping: lane&15 = batch row, (lane>>4)*4+reg = gatecol.
  const int q    = lane >> 4;        // 0..3
  const int rr   = lane & 15;        // batch row within cohort
  const int c0   = (q & 1) << 2;
  const int colq = cs * HCW + c0;
  float bF4[4], bI4[4], bG4[4], bO4[4];
#pragma unroll
  for (int r = 0; r < 4; ++r) {
    bF4[r] = bfv[colq + r]; bI4[r] = biv[colq + r];
    bG4[r] = bcv[colq + r]; bO4[r] = bov[colq + r];
  }

  const int rowb = (rc << 4) + rr;   // this lane's batch row
  const int kb8  = q << 3;
  const float* xbase = xg + (size_t)rowb * S_ * D_;

  // W fragment bases (L2-cached global, bf16, contiguous k):
  const char* WtA = (const char*)Wt + ((size_t)((cs << 5) + rr) << 11);   // gc = rr
  const char* WtB = WtA + (16 << 11);                                     // gc = 16+rr
  // LDS h-fragment base for this lane:
  const char* hfrag = (const char*)hstage + rr * 1040 + (q << 4);
  // LDS staging base for this thread (contiguous 64B):
  char* hput = (char*)hstage + (ti >> 4) * 1040 + ((ti & 15) << 6);

  float cst[4] = {0.f, 0.f, 0.f, 0.f};

  for (int t = 0; t < S_; ++t) {
    const char* hrd = hbc + (t & 1) * (B_ * NCS * 32);
    char*       hwr = hbc + ((t + 1) & 1) * (B_ * NCS * 32);

    f32x4 acc0 = {0.f, 0.f, 0.f, 0.f};   // gatecols [0,16):  f | i
    f32x4 acc1 = {0.f, 0.f, 0.f, 0.f};   // gatecols [16,32): g | o

    const float* xr = xbase + (size_t)t * D_;

    // ---- x-part first (no cross-WG dependency; x reads dedup in the CU's
    //      L1/L2 across the WG's 4 waves) ----
#pragma unroll 4
    for (int ks = 0; ks < 16; ++ks) {
      const int kx = ks * 32 + kb8;
      f32x4 f0 = *(const f32x4*)(xr + kx);
      f32x4 f1 = *(const f32x4*)(xr + kx + 4);
      short8 a;
#pragma unroll
      for (int j = 0; j < 4; ++j) { a[j] = f2bf(f0[j]); a[4 + j] = f2bf(f1[j]); }
      const int kw = 512 + kx;
      short8 b0 = *(const short8*)(WtA + (kw << 1));
      short8 b1 = *(const short8*)(WtB + (kw << 1));
      acc0 = __builtin_amdgcn_mfma_f32_16x16x32_bf16(b0, a, acc0, 0, 0, 0);
      acc1 = __builtin_amdgcn_mfma_f32_16x16x32_bf16(b1, a, acc1, 0, 0, 0);
    }

    // ---- cooperative tagged poll: thread ti owns 8 contiguous records
    //      (128B). Record L = ti*8+j -> (rr=L>>7, cs=(L>>1)&63, q=L&1). ----
    {
      const char* rb = hrd + (rc << 15) + (ti << 7);
      const unsigned int tgt = (unsigned int)t;
      U128 r0, r1, r2, r3, r4, r5, r6, r7;
      while (true) {
        asm volatile(
          "global_load_dwordx4 %[a0], %[p], off sc1\n\t"
          "global_load_dwordx4 %[a1], %[p], off offset:16 sc1\n\t"
          "global_load_dwordx4 %[a2], %[p], off offset:32 sc1\n\t"
          "global_load_dwordx4 %[a3], %[p], off offset:48 sc1\n\t"
          "global_load_dwordx4 %[a4], %[p], off offset:64 sc1\n\t"
          "global_load_dwordx4 %[a5], %[p], off offset:80 sc1\n\t"
          "global_load_dwordx4 %[a6], %[p], off offset:96 sc1\n\t"
          "global_load_dwordx4 %[a7], %[p], off offset:112 sc1\n\t"
          "s_waitcnt vmcnt(0)"
          : [a0]"=&v"(r0.s), [a1]"=&v"(r1.s), [a2]"=&v"(r2.s),
            [a3]"=&v"(r3.s), [a4]"=&v"(r4.s), [a5]"=&v"(r5.s),
            [a6]"=&v"(r6.s), [a7]"=&v"(r7.s)
          : [p]"v"(rb)
          : "memory");
        const unsigned int bad =
            (r0.w[2] ^ tgt) | (r1.w[2] ^ tgt) | (r2.w[2] ^ tgt) |
            (r3.w[2] ^ tgt) | (r4.w[2] ^ tgt) | (r5.w[2] ^ tgt) |
            (r6.w[2] ^ tgt) | (r7.w[2] ^ tgt);
        const int wok = __all((int)(bad == 0u));
        if (lane == 0) lflag[wid] = wok;
        __syncthreads();
        const int allok = lflag[0] & lflag[1] & lflag[2] & lflag[3];
        if (allok) break;
        __syncthreads();   // protect lflag before next attempt rewrites it
      }
      // stage: 8B data words -> contiguous 64B in the LDS h tile
      U128 w01, w23, w45, w67;
      w01.u[0] = r0.u[0]; w01.u[1] = r1.u[0];
      w23.u[0] = r2.u[0]; w23.u[1] = r3.u[0];
      w45.u[0] = r4.u[0]; w45.u[1] = r5.u[0];
      w67.u[0] = r6.u[0]; w67.u[1] = r7.u[0];
      *(short8*)(hput)      = w01.s;
      *(short8*)(hput + 16) = w23.s;
      *(short8*)(hput + 32) = w45.s;
      *(short8*)(hput + 48) = w67.s;
      __syncthreads();
    }

    // ---- h-part: A-fragments from the shared LDS h tile ----
#pragma unroll
    for (int ks = 0; ks < 16; ++ks) {
      short8 a  = *(const short8*)(hfrag + ks * 64);
      const int k0 = ks * 32 + kb8;
      short8 b0 = *(const short8*)(WtA + (k0 << 1));
      short8 b1 = *(const short8*)(WtB + (k0 << 1));
      acc0 = __builtin_amdgcn_mfma_f32_16x16x32_bf16(b0, a, acc0, 0, 0, 0);
      acc1 = __builtin_amdgcn_mfma_f32_16x16x32_bf16(b1, a, acc1, 0, 0, 0);
    }

    // ---- epilogue: exchange f<->i / g<->o halves across lane^32 ----
    f32x4 x0, x1;
#pragma unroll
    for (int j = 0; j < 4; ++j) {
      x0[j] = __shfl_xor(acc0[j], 32);
      x1[j] = __shfl_xor(acc1[j], 32);
    }
    const bool lo = (q < 2);
    float hv[4];
#pragma unroll
    for (int r = 0; r < 4; ++r) {
      const float sF = (lo ? acc0[r] : x0[r]) + bF4[r];
      const float sI = (lo ? x0[r] : acc0[r]) + bI4[r];
      const float sG = (lo ? acc1[r] : x1[r]) + bG4[r];
      const float sO = (lo ? x1[r] : acc1[r]) + bO4[r];
      const float fg = sigm(sF);
      const float ig = sigm(sI);
      const float gg = tanh_(sG);
      const float og = sigm(sO);
      const float cn = cst[r] * fg + gg * ig;
      cst[r] = cn;
      hv[r] = og * tanh_(cn);
    }

    if (lo) {
      // ---- tagged record broadcast FIRST: {4 bf16, tag=t+1, pad}, 16B ----
      if (t < S_ - 1) {
        unsigned int l32 = (unsigned int)(unsigned short)f2bf(hv[0])
                         | ((unsigned int)(unsigned short)f2bf(hv[1]) << 16);
        unsigned int h32 = (unsigned int)(unsigned short)f2bf(hv[2])
                         | ((unsigned int)(unsigned short)f2bf(hv[3]) << 16);
        U128 u;
        u.w[0] = l32; u.w[1] = h32;
        u.w[2] = (unsigned int)(t + 1); u.w[3] = 0u;
        store_b128_dev(hwr + (((rowb << 6) + cs) << 5) + (q << 4), u.s);
      }

      // ---- out: one 16B store per lane ----
      f32x4 hv4;
#pragma unroll
      for (int r = 0; r < 4; ++r) hv4[r] = hv[r];
      *(f32x4*)(out + (size_t)rowb * ((size_t)S_ * H_) + (size_t)t * H_ + colq) = hv4;
      if (t == S_ - 1) {
        f32x4 c4;
#pragma unroll
        for (int r = 0; r < 4; ++r) c4[r] = cst[r];
        *(f32x4*)(out + (size_t)B_ * S_ * H_ + (size_t)rowb * H_ + colq) = hv4;
        *(f32x4*)(out + (size_t)B_ * S_ * H_ + (size_t)B_ * H_
                      + (size_t)rowb * H_ + colq) = c4;
      }
    }
    // No drain, no flag: tags ride with the data. The next poll's vmcnt(0)
    // drains this step's record stores before parity reuse (per-wave
    // same-address ordering), exactly as in the verified single-wave scheme.
  }
}

extern "C" void kernel_launch(void* const* d_in, const int* in_sizes, int n_in,
                              void* d_out, int out_size, void* d_ws, size_t ws_size,
                              hipStream_t stream) {
  (void)in_sizes; (void)n_in; (void)out_size; (void)ws_size;
  const float* x  = (const float*)d_in[0];
  const float* Wf = (const float*)d_in[1];
  const float* bf = (const float*)d_in[2];
  const float* Wi = (const float*)d_in[3];
  const float* bi = (const float*)d_in[4];
  const float* Wc = (const float*)d_in[5];
  const float* bc = (const float*)d_in[6];
  const float* Wo = (const float*)d_in[7];
  const float* bo = (const float*)d_in[8];
  float* out = (float*)d_out;

  char*  hbc = (char*)d_ws;                        // 256 KB tagged h records
  short* Wt  = (short*)((char*)d_ws + (1 << 20));  // 4 MB transposed bf16 W

  // zero both record parities: tag 0 == h_0 == 0; captured in the graph.
  hipMemsetAsync(d_ws, 0, 2 * B_ * NCS * 32, stream);

  lstm_wprep<<<dim3(8), dim3(256), 0, stream>>>(Wf, Wi, Wc, Wo, Wt);
  lstm_persist<<<dim3(NWG), dim3(NT), 0, stream>>>(
      x, bf, bi, bc, bo, Wt, out, hbc);
}

// Round 10
// 5000.893 us; speedup vs baseline: 3.0998x; 3.0998x over previous
//
#include <hip/hip_runtime.h>
#include <hip/hip_bf16.h>

#define B_   64
#define S_   1024
#define D_   512
#define H_   512
#define NWG  256    // 1 wave per WG -> 1 per CU; 4 row-cohorts x 64 col-slices
#define NCS  64     // column slices
#define HCW  8      // h-columns per col-slice
#define NT   64

typedef __attribute__((ext_vector_type(8))) short short8;
typedef __attribute__((ext_vector_type(4))) float f32x4;

// Swizzled byte offset into the LDS W tile: [gc][k] bf16, row = 2048 B.
__device__ __forceinline__ int wl_byte(int gc, int k) {
  return ((gc << 11) + (k << 1)) ^ ((gc & 7) << 4);
}
__device__ __forceinline__ float sigm(float v) { return 1.0f / (1.0f + __expf(-v)); }
__device__ __forceinline__ float tanh_(float v) { return 1.0f - 2.0f / (__expf(2.0f * v) + 1.0f); }
__device__ __forceinline__ short f2bf(float f) {
  __hip_bfloat16 h = __float2bfloat16(f);
  short s;
  __builtin_memcpy(&s, &h, 2);
  return s;
}

union U128 { unsigned long long u[2]; unsigned int w[4]; short8 s; };

// DEVICE-scope (sc1) 16B store: bypasses the XCD-private L2 (the non-coherent
// boundary), resolves at the on-die LLC. Single transaction -> record atomic.
__device__ __forceinline__ void store_b128_dev(void* p, short8 v) {
  asm volatile("global_store_dwordx4 %0, %1, off sc1" :: "v"(p), "v"(v) : "memory");
}

// Record format (16B, one per (row, cs)): 8 bf16 = h[row][cs*8 .. cs*8+7],
// i.e. exactly one MFMA A-fragment. Step tag (t mod 4) is embedded as the
// LSBs of col0 (bit0) and col4 (bit1) — <=1 ulp (2^-7) perturbation on 2 of
// 8 cols, same order as the existing bf16 broadcast rounding.
// Soundness of mod-4: poll-passing induction bounds slot staleness to
// exactly {t, t-2} (producers can't run >1 step ahead of any consumer; each
// wave's own vmcnt(0) drains its prior-parity stores), which mod 4 separates.

__global__ __launch_bounds__(NT, 1) void lstm_persist(
    const float* __restrict__ xg,
    const float* __restrict__ Wf, const float* __restrict__ bfv,
    const float* __restrict__ Wi, const float* __restrict__ biv,
    const float* __restrict__ Wc, const float* __restrict__ bcv,
    const float* __restrict__ Wo, const float* __restrict__ bov,
    float* __restrict__ out,
    char* __restrict__ hbc)   // [2][64 rows][64 cs][16B] tagged fragment records
{
  __shared__ short Wl[32 * 1024];    // 64 KB: W slice, [gc][k] bf16, swizzled

  const int tid  = threadIdx.x;
  const int wg   = blockIdx.x;
  const int cs   = wg >> 2;          // column slice 0..63
  const int rc   = wg & 3;           // row cohort 0..3 (16 batch rows)
  const int lane = tid;              // single wave

  // ---- one-time: stage this WG's W slice (transposed to [gc][k], bf16) ----
  {
    const float* Wg4[4] = {Wf, Wi, Wc, Wo};
    const int gc  = tid >> 1;        // 0..31
    const int seg = tid & 1;         // k half of 512
    const float* Wsrc = Wg4[gc >> 3];
    const int col = cs * HCW + (gc & 7);
    for (int kk = 0; kk < 512; ++kk) {
      const int k = seg * 512 + kk;
      *(short*)((char*)Wl + wl_byte(gc, k)) = f2bf(Wsrc[(size_t)k * H_ + col]);
    }
  }

  // Transposed-C lane mapping: lane&15 = batch row, (lane>>4)*4+reg = gatecol.
  const int q    = lane >> 4;        // 0..3
  const int rr   = lane & 15;        // batch row within wave tile
  const int c0   = (q & 1) << 2;     // col-quad base within slice's 8 cols
  const int colq = cs * HCW + c0;    // global col-quad base
  float bF4[4], bI4[4], bG4[4], bO4[4];
#pragma unroll
  for (int r = 0; r < 4; ++r) {
    bF4[r] = bfv[colq + r]; bI4[r] = biv[colq + r];
    bG4[r] = bcv[colq + r]; bO4[r] = bov[colq + r];
  }

  __syncthreads();                   // Wl ready (single wave; effectively free)

  const int rowb = (rc << 4) + rr;   // this lane's batch row
  const int kb8  = q << 3;
  const float* xbase = xg + (size_t)rowb * S_ * D_;

  float cst[4] = {0.f, 0.f, 0.f, 0.f};   // cell state: 4 cols of row rowb

  for (int t = 0; t < S_; ++t) {
    const char* hrd = hbc + (t & 1) * (B_ * NCS * 16);
    char*       hwr = hbc + ((t + 1) & 1) * (B_ * NCS * 16);

    f32x4 acc0 = {0.f, 0.f, 0.f, 0.f};   // gatecols [0,16):  f | i
    f32x4 acc1 = {0.f, 0.f, 0.f, 0.f};   // gatecols [16,32): g | o

    const float* xr = xbase + (size_t)t * D_;

    // ---- x-part first (no cross-WG dependency) ----
#pragma unroll 4
    for (int ks = 0; ks < 16; ++ks) {
      const int kx = ks * 32 + kb8;
      f32x4 f0 = *(const f32x4*)(xr + kx);
      f32x4 f1 = *(const f32x4*)(xr + kx + 4);
      short8 a;
#pragma unroll
      for (int j = 0; j < 4; ++j) { a[j] = f2bf(f0[j]); a[4 + j] = f2bf(f1[j]); }
      const int kw = 512 + kx;
      short8 b0 = *(const short8*)((const char*)Wl + wl_byte(lane & 15, kw));
      short8 b1 = *(const short8*)((const char*)Wl + wl_byte(16 + (lane & 15), kw));
      acc0 = __builtin_amdgcn_mfma_f32_16x16x32_bf16(b0, a, acc0, 0, 0, 0);
      acc1 = __builtin_amdgcn_mfma_f32_16x16x32_bf16(b1, a, acc1, 0, 0, 0);
    }

    // ---- h-part: poll tagged fragment records (detection == data load).
    //      Lane needs records (rowb, cs = 4*ks + q), ks=0..15: base
    //      rowb*1024 + q*16, stride 64B -> 16 loads (half of before), and
    //      the 4 q-groups' 16B chunks share 64B lines per instruction
    //      (intra-instruction coalescing). vmcnt(0) also drains our
    //      previous-step record stores (same-address parity reuse). ----
    {
      const char* rb = hrd + (rowb << 10) + (q << 4);
      const unsigned int t0 = (unsigned int)t;        // bit0 target
      const unsigned int t1 = (unsigned int)t >> 1;   // bit1 target
      U128 rc0, rc1, rc2, rc3, rc4, rc5, rc6, rc7,
           rc8, rc9, rc10, rc11, rc12, rc13, rc14, rc15;
      while (true) {
        asm volatile(
          "global_load_dwordx4 %[r0], %[p], off sc1\n\t"
          "global_load_dwordx4 %[r1], %[p], off offset:64 sc1\n\t"
          "global_load_dwordx4 %[r2], %[p], off offset:128 sc1\n\t"
          "global_load_dwordx4 %[r3], %[p], off offset:192 sc1\n\t"
          "global_load_dwordx4 %[r4], %[p], off offset:256 sc1\n\t"
          "global_load_dwordx4 %[r5], %[p], off offset:320 sc1\n\t"
          "global_load_dwordx4 %[r6], %[p], off offset:384 sc1\n\t"
          "global_load_dwordx4 %[r7], %[p], off offset:448 sc1\n\t"
          "global_load_dwordx4 %[r8], %[p], off offset:512 sc1\n\t"
          "global_load_dwordx4 %[r9], %[p], off offset:576 sc1\n\t"
          "global_load_dwordx4 %[r10], %[p], off offset:640 sc1\n\t"
          "global_load_dwordx4 %[r11], %[p], off offset:704 sc1\n\t"
          "global_load_dwordx4 %[r12], %[p], off offset:768 sc1\n\t"
          "global_load_dwordx4 %[r13], %[p], off offset:832 sc1\n\t"
          "global_load_dwordx4 %[r14], %[p], off offset:896 sc1\n\t"
          "global_load_dwordx4 %[r15], %[p], off offset:960 sc1\n\t"
          "s_waitcnt vmcnt(0)"
          : [r0]"=&v"(rc0.s), [r1]"=&v"(rc1.s), [r2]"=&v"(rc2.s),
            [r3]"=&v"(rc3.s), [r4]"=&v"(rc4.s), [r5]"=&v"(rc5.s),
            [r6]"=&v"(rc6.s), [r7]"=&v"(rc7.s), [r8]"=&v"(rc8.s),
            [r9]"=&v"(rc9.s), [r10]"=&v"(rc10.s), [r11]"=&v"(rc11.s),
            [r12]"=&v"(rc12.s), [r13]"=&v"(rc13.s), [r14]"=&v"(rc14.s),
            [r15]"=&v"(rc15.s)
          : [p]"v"(rb)
          : "memory");
        // tag bits: bit0 = LSB of col0 (w[0]), bit1 = LSB of col4 (w[2])
#define TCHK(R) ( ((R.w[0] ^ t0) & 1u) | ((R.w[2] ^ t1) & 1u) )
        const unsigned int bad =
            TCHK(rc0)  | TCHK(rc1)  | TCHK(rc2)  | TCHK(rc3)  |
            TCHK(rc4)  | TCHK(rc5)  | TCHK(rc6)  | TCHK(rc7)  |
            TCHK(rc8)  | TCHK(rc9)  | TCHK(rc10) | TCHK(rc11) |
            TCHK(rc12) | TCHK(rc13) | TCHK(rc14) | TCHK(rc15);
#undef TCHK
        if (__all((int)(bad == 0u))) break;
      }

      // Two independent 8-deep MFMA chains per acc (halve latency exposure).
      f32x4 acc0b = {0.f, 0.f, 0.f, 0.f};
      f32x4 acc1b = {0.f, 0.f, 0.f, 0.f};
#define HSTEP(KS, RA, A0, A1)                                                  \
      {                                                                        \
        const int k0_ = (KS) * 32 + kb8;                                       \
        short8 b0_ = *(const short8*)((const char*)Wl + wl_byte(lane & 15, k0_)); \
        short8 b1_ = *(const short8*)((const char*)Wl + wl_byte(16 + (lane & 15), k0_)); \
        A0 = __builtin_amdgcn_mfma_f32_16x16x32_bf16(b0_, RA.s, A0, 0, 0, 0);  \
        A1 = __builtin_amdgcn_mfma_f32_16x16x32_bf16(b1_, RA.s, A1, 0, 0, 0);  \
      }
      HSTEP(0,  rc0,  acc0,  acc1)  HSTEP(1,  rc1,  acc0b, acc1b)
      HSTEP(2,  rc2,  acc0,  acc1)  HSTEP(3,  rc3,  acc0b, acc1b)
      HSTEP(4,  rc4,  acc0,  acc1)  HSTEP(5,  rc5,  acc0b, acc1b)
      HSTEP(6,  rc6,  acc0,  acc1)  HSTEP(7,  rc7,  acc0b, acc1b)
      HSTEP(8,  rc8,  acc0,  acc1)  HSTEP(9,  rc9,  acc0b, acc1b)
      HSTEP(10, rc10, acc0,  acc1)  HSTEP(11, rc11, acc0b, acc1b)
      HSTEP(12, rc12, acc0,  acc1)  HSTEP(13, rc13, acc0b, acc1b)
      HSTEP(14, rc14, acc0,  acc1)  HSTEP(15, rc15, acc0b, acc1b)
#undef HSTEP
#pragma unroll
      for (int j = 0; j < 4; ++j) { acc0[j] += acc0b[j]; acc1[j] += acc1b[j]; }
    }

    // ---- epilogue: exchange f<->i / g<->o halves across lane^32 ----
    f32x4 x0, x1;
#pragma unroll
    for (int j = 0; j < 4; ++j) {
      x0[j] = __shfl_xor(acc0[j], 32);
      x1[j] = __shfl_xor(acc1[j], 32);
    }
    const bool lo = (q < 2);
    float hv[4];
#pragma unroll
    for (int r = 0; r < 4; ++r) {
      const float sF = (lo ? acc0[r] : x0[r]) + bF4[r];
      const float sI = (lo ? x0[r] : acc0[r]) + bI4[r];
      const float sG = (lo ? acc1[r] : x1[r]) + bG4[r];
      const float sO = (lo ? x1[r] : acc1[r]) + bO4[r];
      const float fg = sigm(sF);
      const float ig = sigm(sI);
      const float gg = tanh_(sG);
      const float og = sigm(sO);
      const float cn = cst[r] * fg + gg * ig;
      cst[r] = cn;
      hv[r] = og * tanh_(cn);
    }

    // ---- record broadcast: merge the two col-quads of this cs across
    //      lane^16, embed tag bits, ONE 16B store per row (q==0 lanes) ----
    unsigned long long hp8;
    {
      unsigned int l32 = (unsigned int)(unsigned short)f2bf(hv[0])
                       | ((unsigned int)(unsigned short)f2bf(hv[1]) << 16);
      unsigned int h32 = (unsigned int)(unsigned short)f2bf(hv[2])
                       | ((unsigned int)(unsigned short)f2bf(hv[3]) << 16);
      hp8 = (unsigned long long)l32 | ((unsigned long long)h32 << 32);
    }
    unsigned long long other = __shfl_xor(hp8, 16);  // partner quad, same row
    if (q == 0 && t < S_ - 1) {
      const unsigned int tag = (unsigned int)(t + 1);
      U128 u;
      u.w[0] = ((unsigned int)hp8 & ~1u) | (tag & 1u);          // col0 LSB=bit0
      u.w[1] = (unsigned int)(hp8 >> 32);
      u.w[2] = ((unsigned int)other & ~1u) | ((tag >> 1) & 1u); // col4 LSB=bit1
      u.w[3] = (unsigned int)(other >> 32);
      store_b128_dev(hwr + (rowb << 10) + (cs << 4), u.s);
    }

    if (lo) {
      // ---- out: one 16B store per lane (4 consecutive cols of row rowb),
      //      full-precision f32 (tag bits only live in the bf16 broadcast) ----
      f32x4 hv4;
#pragma unroll
      for (int r = 0; r < 4; ++r) hv4[r] = hv[r];
      *(f32x4*)(out + (size_t)rowb * ((size_t)S_ * H_) + (size_t)t * H_ + colq) = hv4;
      if (t == S_ - 1) {
        f32x4 c4;
#pragma unroll
        for (int r = 0; r < 4; ++r) c4[r] = cst[r];
        *(f32x4*)(out + (size_t)B_ * S_ * H_ + (size_t)rowb * H_ + colq) = hv4;
        *(f32x4*)(out + (size_t)B_ * S_ * H_ + (size_t)B_ * H_
                      + (size_t)rowb * H_ + colq) = c4;
      }
    }
    // No drain, no flag, no barrier: tags ride with the data.
  }
}

extern "C" void kernel_launch(void* const* d_in, const int* in_sizes, int n_in,
                              void* d_out, int out_size, void* d_ws, size_t ws_size,
                              hipStream_t stream) {
  (void)in_sizes; (void)n_in; (void)out_size; (void)ws_size;
  const float* x  = (const float*)d_in[0];
  const float* Wf = (const float*)d_in[1];
  const float* bf = (const float*)d_in[2];
  const float* Wi = (const float*)d_in[3];
  const float* bi = (const float*)d_in[4];
  const float* Wc = (const float*)d_in[5];
  const float* bc = (const float*)d_in[6];
  const float* Wo = (const float*)d_in[7];
  const float* bo = (const float*)d_in[8];
  float* out = (float*)d_out;

  char* hbc = (char*)d_ws;   // 128 KB: [2][64][64][16B] tagged fragment records

  // zero both parities: tag bits 0 == t=0 mod 4, data 0 == h_0; captured in
  // the graph, so every replay starts from a clean state.
  hipMemsetAsync(d_ws, 0, 2 * B_ * NCS * 16, stream);

  lstm_persist<<<dim3(NWG), dim3(NT), 0, stream>>>(
      x, Wf, bf, Wi, bi, Wc, bc, Wo, bo, out, hbc);
}

// Round 11
// 4153.276 us; speedup vs baseline: 3.7324x; 1.2041x over previous
//
#include <hip/hip_runtime.h>
#include <hip/hip_bf16.h>

#define B_   64
#define S_   1024
#define D_   512
#define H_   512
#define NWG  256    // 1 wave per WG -> 1 per CU; 4 row-cohorts x 64 col-slices
#define NCS  64     // column slices
#define HCW  8      // h-columns per col-slice
#define NT   64

typedef __attribute__((ext_vector_type(8))) short short8;
typedef __attribute__((ext_vector_type(4))) float f32x4;

// Swizzled byte offset into the LDS W tile: [gc][k] bf16, row = 2048 B.
__device__ __forceinline__ int wl_byte(int gc, int k) {
  return ((gc << 11) + (k << 1)) ^ ((gc & 7) << 4);
}
__device__ __forceinline__ float sigm(float v) { return 1.0f / (1.0f + __expf(-v)); }
__device__ __forceinline__ float tanh_(float v) { return 1.0f - 2.0f / (__expf(2.0f * v) + 1.0f); }
__device__ __forceinline__ short f2bf(float f) {
  __hip_bfloat16 h = __float2bfloat16(f);
  short s;
  __builtin_memcpy(&s, &h, 2);
  return s;
}

union U128 { unsigned long long u[2]; unsigned int w[4]; short8 s; };

// DEVICE-scope (sc1) 16B store: bypasses the XCD-private L2 (the non-coherent
// boundary), resolves at the on-die LLC. Single transaction -> record atomic
// (MUST stay one dwordx4: tag bit1 lives in col4; halves written separately
// could pass the check with a stale low half).
__device__ __forceinline__ void store_b128_dev(void* p, short8 v) {
  asm volatile("global_store_dwordx4 %0, %1, off sc1" :: "v"(p), "v"(v) : "memory");
}

// ---------------------------------------------------------------------------
// Prep: xb = bf16(x), same [B][S][D] layout. Removes 128 f2bf VALU ops and
// half the x load bytes from every step of the persistent loop. Values are
// bit-identical to the inline conversion the loop used to do.
// ---------------------------------------------------------------------------
__global__ __launch_bounds__(256, 1) void lstm_xprep(
    const float* __restrict__ xg, short* __restrict__ xb)
{
  const size_t i = ((size_t)blockIdx.x * 256 + threadIdx.x) * 8;
  f32x4 a = *(const f32x4*)(xg + i);
  f32x4 b = *(const f32x4*)(xg + i + 4);
  short8 v;
#pragma unroll
  for (int j = 0; j < 4; ++j) { v[j] = f2bf(a[j]); v[4 + j] = f2bf(b[j]); }
  *(short8*)(xb + i) = v;
}

// Record format (16B, one per (row, cs)): 8 bf16 = h[row][cs*8 .. cs*8+7],
// i.e. exactly one MFMA A-fragment. Step tag (t mod 4) is embedded as the
// LSBs of col0 (bit0) and col4 (bit1) — <=1 ulp (2^-7) perturbation on 2 of
// 8 cols. Poll-passing induction bounds slot staleness to {t, t-2}, which
// bit1 separates (16B single-transaction store keeps both halves coherent).

template<int USE_XB>
__global__ __launch_bounds__(NT, 1) void lstm_persist(
    const float* __restrict__ xg, const short* __restrict__ xb,
    const float* __restrict__ Wf, const float* __restrict__ bfv,
    const float* __restrict__ Wi, const float* __restrict__ biv,
    const float* __restrict__ Wc, const float* __restrict__ bcv,
    const float* __restrict__ Wo, const float* __restrict__ bov,
    float* __restrict__ out,
    char* __restrict__ hbc)   // [2][64 rows][64 cs][16B] tagged fragment records
{
  __shared__ short Wl[32 * 1024];    // 64 KB: W slice, [gc][k] bf16, swizzled

  const int tid  = threadIdx.x;
  const int wg   = blockIdx.x;
  const int cs   = wg >> 2;          // column slice 0..63
  const int rc   = wg & 3;           // row cohort 0..3 (16 batch rows)
  const int lane = tid;              // single wave

  // ---- one-time: stage this WG's W slice (transposed to [gc][k], bf16) ----
  {
    const float* Wg4[4] = {Wf, Wi, Wc, Wo};
    const int gc  = tid >> 1;        // 0..31
    const int seg = tid & 1;         // k half of 512
    const float* Wsrc = Wg4[gc >> 3];
    const int col = cs * HCW + (gc & 7);
    for (int kk = 0; kk < 512; ++kk) {
      const int k = seg * 512 + kk;
      *(short*)((char*)Wl + wl_byte(gc, k)) = f2bf(Wsrc[(size_t)k * H_ + col]);
    }
  }

  // Transposed-C lane mapping: lane&15 = batch row, (lane>>4)*4+reg = gatecol.
  const int q    = lane >> 4;        // 0..3
  const int rr   = lane & 15;        // batch row within wave tile
  const int c0   = (q & 1) << 2;     // col-quad base within slice's 8 cols
  const int colq = cs * HCW + c0;    // global col-quad base
  float bF4[4], bI4[4], bG4[4], bO4[4];
#pragma unroll
  for (int r = 0; r < 4; ++r) {
    bF4[r] = bfv[colq + r]; bI4[r] = biv[colq + r];
    bG4[r] = bcv[colq + r]; bO4[r] = bov[colq + r];
  }

  __syncthreads();                   // Wl ready (single wave; effectively free)

  const int rowb = (rc << 4) + rr;   // this lane's batch row
  const int kb8  = q << 3;

  float cst[4] = {0.f, 0.f, 0.f, 0.f};   // cell state: 4 cols of row rowb

  for (int t = 0; t < S_; ++t) {
    const char* hrd = hbc + (t & 1) * (B_ * NCS * 16);
    char*       hwr = hbc + ((t + 1) & 1) * (B_ * NCS * 16);

    f32x4 acc0 = {0.f, 0.f, 0.f, 0.f};   // gatecols [0,16):  f | i
    f32x4 acc1 = {0.f, 0.f, 0.f, 0.f};   // gatecols [16,32): g | o

    // ---- x-part first (no cross-WG dependency) ----
    if constexpr (USE_XB) {
      const short* xr = xb + (size_t)rowb * S_ * D_ + (size_t)t * D_;
#pragma unroll 4
      for (int ks = 0; ks < 16; ++ks) {
        const int kx = ks * 32 + kb8;
        short8 a = *(const short8*)(xr + kx);   // 16B coalesced bf16, no cvt
        const int kw = 512 + kx;
        short8 b0 = *(const short8*)((const char*)Wl + wl_byte(lane & 15, kw));
        short8 b1 = *(const short8*)((const char*)Wl + wl_byte(16 + (lane & 15), kw));
        acc0 = __builtin_amdgcn_mfma_f32_16x16x32_bf16(b0, a, acc0, 0, 0, 0);
        acc1 = __builtin_amdgcn_mfma_f32_16x16x32_bf16(b1, a, acc1, 0, 0, 0);
      }
    } else {
      const float* xr = xg + (size_t)rowb * S_ * D_ + (size_t)t * D_;
#pragma unroll 4
      for (int ks = 0; ks < 16; ++ks) {
        const int kx = ks * 32 + kb8;
        f32x4 f0 = *(const f32x4*)(xr + kx);
        f32x4 f1 = *(const f32x4*)(xr + kx + 4);
        short8 a;
#pragma unroll
        for (int j = 0; j < 4; ++j) { a[j] = f2bf(f0[j]); a[4 + j] = f2bf(f1[j]); }
        const int kw = 512 + kx;
        short8 b0 = *(const short8*)((const char*)Wl + wl_byte(lane & 15, kw));
        short8 b1 = *(const short8*)((const char*)Wl + wl_byte(16 + (lane & 15), kw));
        acc0 = __builtin_amdgcn_mfma_f32_16x16x32_bf16(b0, a, acc0, 0, 0, 0);
        acc1 = __builtin_amdgcn_mfma_f32_16x16x32_bf16(b1, a, acc1, 0, 0, 0);
      }
    }

    // ---- h-part: poll tagged fragment records (detection == data load).
    //      Lane needs records (rowb, cs = 4*ks + q), ks=0..15: base
    //      rowb*1024 + q*16, stride 64B -> 16 loads, 4 q-groups share 64B
    //      lines per instruction. vmcnt(0) also drains our previous-step
    //      record stores (same-address parity reuse). ----
    {
      const char* rb = hrd + (rowb << 10) + (q << 4);
      const unsigned int t0 = (unsigned int)t;        // bit0 target
      const unsigned int t1 = (unsigned int)t >> 1;   // bit1 target
      U128 rc0, rc1, rc2, rc3, rc4, rc5, rc6, rc7,
           rc8, rc9, rc10, rc11, rc12, rc13, rc14, rc15;
      while (true) {
        asm volatile(
          "global_load_dwordx4 %[r0], %[p], off sc1\n\t"
          "global_load_dwordx4 %[r1], %[p], off offset:64 sc1\n\t"
          "global_load_dwordx4 %[r2], %[p], off offset:128 sc1\n\t"
          "global_load_dwordx4 %[r3], %[p], off offset:192 sc1\n\t"
          "global_load_dwordx4 %[r4], %[p], off offset:256 sc1\n\t"
          "global_load_dwordx4 %[r5], %[p], off offset:320 sc1\n\t"
          "global_load_dwordx4 %[r6], %[p], off offset:384 sc1\n\t"
          "global_load_dwordx4 %[r7], %[p], off offset:448 sc1\n\t"
          "global_load_dwordx4 %[r8], %[p], off offset:512 sc1\n\t"
          "global_load_dwordx4 %[r9], %[p], off offset:576 sc1\n\t"
          "global_load_dwordx4 %[r10], %[p], off offset:640 sc1\n\t"
          "global_load_dwordx4 %[r11], %[p], off offset:704 sc1\n\t"
          "global_load_dwordx4 %[r12], %[p], off offset:768 sc1\n\t"
          "global_load_dwordx4 %[r13], %[p], off offset:832 sc1\n\t"
          "global_load_dwordx4 %[r14], %[p], off offset:896 sc1\n\t"
          "global_load_dwordx4 %[r15], %[p], off offset:960 sc1\n\t"
          "s_waitcnt vmcnt(0)"
          : [r0]"=&v"(rc0.s), [r1]"=&v"(rc1.s), [r2]"=&v"(rc2.s),
            [r3]"=&v"(rc3.s), [r4]"=&v"(rc4.s), [r5]"=&v"(rc5.s),
            [r6]"=&v"(rc6.s), [r7]"=&v"(rc7.s), [r8]"=&v"(rc8.s),
            [r9]"=&v"(rc9.s), [r10]"=&v"(rc10.s), [r11]"=&v"(rc11.s),
            [r12]"=&v"(rc12.s), [r13]"=&v"(rc13.s), [r14]"=&v"(rc14.s),
            [r15]"=&v"(rc15.s)
          : [p]"v"(rb)
          : "memory");
        // tag bits: bit0 = LSB of col0 (w[0]), bit1 = LSB of col4 (w[2])
#define TCHK(R) ( ((R.w[0] ^ t0) & 1u) | ((R.w[2] ^ t1) & 1u) )
        const unsigned int bad =
            TCHK(rc0)  | TCHK(rc1)  | TCHK(rc2)  | TCHK(rc3)  |
            TCHK(rc4)  | TCHK(rc5)  | TCHK(rc6)  | TCHK(rc7)  |
            TCHK(rc8)  | TCHK(rc9)  | TCHK(rc10) | TCHK(rc11) |
            TCHK(rc12) | TCHK(rc13) | TCHK(rc14) | TCHK(rc15);
#undef TCHK
        if (__all((int)(bad == 0u))) break;
      }

      // Two independent 8-deep MFMA chains per acc (halve latency exposure).
      f32x4 acc0b = {0.f, 0.f, 0.f, 0.f};
      f32x4 acc1b = {0.f, 0.f, 0.f, 0.f};
#define HSTEP(KS, RA, A0, A1)                                                  \
      {                                                                        \
        const int k0_ = (KS) * 32 + kb8;                                       \
        short8 b0_ = *(const short8*)((const char*)Wl + wl_byte(lane & 15, k0_)); \
        short8 b1_ = *(const short8*)((const char*)Wl + wl_byte(16 + (lane & 15), k0_)); \
        A0 = __builtin_amdgcn_mfma_f32_16x16x32_bf16(b0_, RA.s, A0, 0, 0, 0);  \
        A1 = __builtin_amdgcn_mfma_f32_16x16x32_bf16(b1_, RA.s, A1, 0, 0, 0);  \
      }
      HSTEP(0,  rc0,  acc0,  acc1)  HSTEP(1,  rc1,  acc0b, acc1b)
      HSTEP(2,  rc2,  acc0,  acc1)  HSTEP(3,  rc3,  acc0b, acc1b)
      HSTEP(4,  rc4,  acc0,  acc1)  HSTEP(5,  rc5,  acc0b, acc1b)
      HSTEP(6,  rc6,  acc0,  acc1)  HSTEP(7,  rc7,  acc0b, acc1b)
      HSTEP(8,  rc8,  acc0,  acc1)  HSTEP(9,  rc9,  acc0b, acc1b)
      HSTEP(10, rc10, acc0,  acc1)  HSTEP(11, rc11, acc0b, acc1b)
      HSTEP(12, rc12, acc0,  acc1)  HSTEP(13, rc13, acc0b, acc1b)
      HSTEP(14, rc14, acc0,  acc1)  HSTEP(15, rc15, acc0b, acc1b)
#undef HSTEP
#pragma unroll
      for (int j = 0; j < 4; ++j) { acc0[j] += acc0b[j]; acc1[j] += acc1b[j]; }
    }

    // ---- epilogue: exchange f<->i / g<->o halves across lane^32 ----
    f32x4 x0, x1;
#pragma unroll
    for (int j = 0; j < 4; ++j) {
      x0[j] = __shfl_xor(acc0[j], 32);
      x1[j] = __shfl_xor(acc1[j], 32);
    }
    const bool lo = (q < 2);
    float hv[4];
#pragma unroll
    for (int r = 0; r < 4; ++r) {
      const float sF = (lo ? acc0[r] : x0[r]) + bF4[r];
      const float sI = (lo ? x0[r] : acc0[r]) + bI4[r];
      const float sG = (lo ? acc1[r] : x1[r]) + bG4[r];
      const float sO = (lo ? x1[r] : acc1[r]) + bO4[r];
      const float fg = sigm(sF);
      const float ig = sigm(sI);
      const float gg = tanh_(sG);
      const float og = sigm(sO);
      const float cn = cst[r] * fg + gg * ig;
      cst[r] = cn;
      hv[r] = og * tanh_(cn);
    }

    // ---- record broadcast: merge the two col-quads of this cs across
    //      lane^16, embed tag bits, ONE 16B store per row (q==0 lanes) ----
    unsigned long long hp8;
    {
      unsigned int l32 = (unsigned int)(unsigned short)f2bf(hv[0])
                       | ((unsigned int)(unsigned short)f2bf(hv[1]) << 16);
      unsigned int h32 = (unsigned int)(unsigned short)f2bf(hv[2])
                       | ((unsigned int)(unsigned short)f2bf(hv[3]) << 16);
      hp8 = (unsigned long long)l32 | ((unsigned long long)h32 << 32);
    }
    unsigned long long other = __shfl_xor(hp8, 16);  // partner quad, same row
    if (q == 0 && t < S_ - 1) {
      const unsigned int tag = (unsigned int)(t + 1);
      U128 u;
      u.w[0] = ((unsigned int)hp8 & ~1u) | (tag & 1u);          // col0 LSB=bit0
      u.w[1] = (unsigned int)(hp8 >> 32);
      u.w[2] = ((unsigned int)other & ~1u) | ((tag >> 1) & 1u); // col4 LSB=bit1
      u.w[3] = (unsigned int)(other >> 32);
      store_b128_dev(hwr + (rowb << 10) + (cs << 4), u.s);
    }

    if (lo) {
      // ---- out: one 16B store per lane (4 consecutive cols of row rowb),
      //      full-precision f32 (tag bits only live in the bf16 broadcast) ----
      f32x4 hv4;
#pragma unroll
      for (int r = 0; r < 4; ++r) hv4[r] = hv[r];
      *(f32x4*)(out + (size_t)rowb * ((size_t)S_ * H_) + (size_t)t * H_ + colq) = hv4;
      if (t == S_ - 1) {
        f32x4 c4;
#pragma unroll
        for (int r = 0; r < 4; ++r) c4[r] = cst[r];
        *(f32x4*)(out + (size_t)B_ * S_ * H_ + (size_t)rowb * H_ + colq) = hv4;
        *(f32x4*)(out + (size_t)B_ * S_ * H_ + (size_t)B_ * H_
                      + (size_t)rowb * H_ + colq) = c4;
      }
    }
    // No drain, no flag, no barrier: tags ride with the data.
  }
}

extern "C" void kernel_launch(void* const* d_in, const int* in_sizes, int n_in,
                              void* d_out, int out_size, void* d_ws, size_t ws_size,
                              hipStream_t stream) {
  (void)in_sizes; (void)n_in; (void)out_size;
  const float* x  = (const float*)d_in[0];
  const float* Wf = (const float*)d_in[1];
  const float* bf = (const float*)d_in[2];
  const float* Wi = (const float*)d_in[3];
  const float* bi = (const float*)d_in[4];
  const float* Wc = (const float*)d_in[5];
  const float* bc = (const float*)d_in[6];
  const float* Wo = (const float*)d_in[7];
  const float* bo = (const float*)d_in[8];
  float* out = (float*)d_out;

  char* hbc = (char*)d_ws;   // 128 KB: [2][64][64][16B] tagged fragment records

  const size_t XB_OFF   = (size_t)1 << 20;                        // 1 MB
  const size_t XB_BYTES = (size_t)B_ * S_ * D_ * sizeof(short);   // 64 MB

  // zero both parities: tag bits 0 == t=0 mod 4, data 0 == h_0; captured in
  // the graph, so every replay starts from a clean state.
  hipMemsetAsync(d_ws, 0, 2 * B_ * NCS * 16, stream);

  if (ws_size >= XB_OFF + XB_BYTES) {
    short* xb = (short*)((char*)d_ws + XB_OFF);
    lstm_xprep<<<dim3((B_ * S_ * D_) / (256 * 8)), dim3(256), 0, stream>>>(x, xb);
    lstm_persist<1><<<dim3(NWG), dim3(NT), 0, stream>>>(
        x, xb, Wf, bf, Wi, bi, Wc, bc, Wo, bo, out, hbc);
  } else {
    lstm_persist<0><<<dim3(NWG), dim3(NT), 0, stream>>>(
        x, nullptr, Wf, bf, Wi, bi, Wc, bc, Wo, bo, out, hbc);
  }
}